// Round 7
// baseline (216.764 us; speedup 1.0000x reference)
//
#include <hip/hip_runtime.h>

#define N_NODES 50000
#define N_EDGES 800000
#define IN_F 256
#define OUT_F 128

#define CHUNKS 128
#define EPC (N_EDGES / CHUNKS)   // 6250 edges per chunk
#define BINW (N_NODES / 4)       // 12500 u32 words, 4 x u8 bins each (50 KB LDS)
#define NGB 196                  // node-group blocks (256 nodes each)
#define HIST_BLOCKS (2 * CHUNKS) // 256

typedef __attribute__((ext_vector_type(8))) short short8;
typedef __attribute__((ext_vector_type(4))) float float4_t;

// float -> bf16 round-to-nearest-even
__device__ __forceinline__ short f2bf(float f) {
  unsigned u = __builtin_bit_cast(unsigned, f);
  u = u + 0x7FFFu + ((u >> 16) & 1u);
  return (short)(u >> 16);
}

__device__ __forceinline__ float bflo(unsigned u) {
  return __builtin_bit_cast(float, u << 16);
}
__device__ __forceinline__ float bfhi(unsigned u) {
  return __builtin_bit_cast(float, u & 0xFFFF0000u);
}

// ---- histogram + per-edge rank (LDS-privatized u8 bins) + fused wprep ----
// blocks 0..255: b>>7 = side (0:dst, 1:src), b&127 = chunk. blocks 256..257: wprep.
// Counts per (chunk,node) are tiny (lambda = EPC/N = 0.125), so u8 bins packed
// 4-per-u32 cover ALL 50000 nodes in one 50 KB LDS pass (keys read once).
__global__ __launch_bounds__(256) void hist_kernel(const int* __restrict__ src,
                                                   const int* __restrict__ dst,
                                                   unsigned char* __restrict__ pdst8,
                                                   unsigned char* __restrict__ psrc8,
                                                   unsigned char* __restrict__ rank8,
                                                   const float* __restrict__ W,
                                                   short* __restrict__ Wf,
                                                   int* __restrict__ cursor) {
  __shared__ unsigned bins[BINW];
  int b = blockIdx.x;
  int t = threadIdx.x;
  if (b >= HIST_BLOCKS) {  // wprep: 2 blocks cover 32768 elements; also zero cursor
    int bb = b - HIST_BLOCKS;
    if (bb == 0 && t == 0) *cursor = 0;
#pragma unroll
    for (int i = 0; i < 64; ++i) {
      int idx = bb * 16384 + i * 256 + t;
      int k = idx >> 7, n = idx & 127;
      int s = k >> 5, q = (k >> 3) & 3, j = k & 7;
      int tt = n >> 4, m = n & 15;
      Wf[(((s * 8 + tt) * 16 + m) * 32) + q * 8 + j] = f2bf(W[idx]);
    }
    return;
  }
  int h = b >> 7;
  int c = b & 127;
  for (int j = t; j < BINW; j += 256) bins[j] = 0;
  __syncthreads();
  const int* key = h ? src : dst;
  int e0 = c * EPC;

  auto process = [&](int v, int eI) {
    unsigned sh = (v & 3) * 8;
    unsigned old = atomicAdd(&bins[v >> 2], 1u << sh);
    if (!h) rank8[eI] = (unsigned char)((old >> sh) & 0xFFu);
  };

  // 6 full tiles of 1024 + tail of 106 (EPC = 6250)
#pragma unroll 2
  for (int tile = 0; tile < 6; ++tile) {
    int i = tile * 1024 + t;
    int k0 = key[e0 + i];
    int k1 = key[e0 + i + 256];
    int k2 = key[e0 + i + 512];
    int k3 = key[e0 + i + 768];
    process(k0, e0 + i);
    process(k1, e0 + i + 256);
    process(k2, e0 + i + 512);
    process(k3, e0 + i + 768);
  }
  {
    int i = 6144 + t;
    if (i < EPC) process(key[e0 + i], e0 + i);
  }
  __syncthreads();
  unsigned* p32 = (unsigned*)((h ? psrc8 : pdst8) + (size_t)c * N_NODES);
  for (int j = t; j < BINW; j += 256) p32[j] = bins[j];
}

// grid (NGB, 2).
// side 0: delta8 (intra-node chunk prefix), cnt, row_start (base via device atomic —
//         segment bases are arrival-ordered, which is fine since agg uses rs+cnt).
// side 1: norm = 1/max(out_deg,1).
__global__ __launch_bounds__(256) void reduceoff_kernel(const unsigned char* __restrict__ pdst8,
                                                        const unsigned char* __restrict__ psrc8,
                                                        unsigned char* __restrict__ delta8,
                                                        int* __restrict__ cnt,
                                                        int* __restrict__ row_start,
                                                        int* __restrict__ cursor,
                                                        float* __restrict__ norm) {
  int g = blockIdx.x, side = blockIdx.y;
  int t = threadIdx.x;
  int v = g * 256 + t;
  bool ok = v < N_NODES;
  if (side == 0) {
    int run = 0;
#pragma unroll
    for (int c = 0; c < CHUNKS; ++c) {
      int d = ok ? (int)pdst8[(size_t)c * N_NODES + v] : 0;
      if (ok) delta8[(size_t)c * N_NODES + v] = (unsigned char)run;
      run += d;
    }
    if (ok) cnt[v] = run;
    // block-exclusive prefix of per-thread totals
    int l = t & 63, w = t >> 6;
    int x = run;
    for (int off = 1; off < 64; off <<= 1) {
      int y = __shfl_up(x, off);
      if (l >= off) x += y;
    }
    __shared__ int wp[4];
    __shared__ int sbase;
    if (l == 63) wp[w] = x;
    __syncthreads();
    int add = 0;
    for (int i = 0; i < w; ++i) add += wp[i];
    if (t == 0) sbase = atomicAdd(cursor, wp[0] + wp[1] + wp[2] + wp[3]);
    __syncthreads();
    if (ok) row_start[v] = sbase + add + x - run;
  } else {
    int gsum = 0;
#pragma unroll
    for (int c = 0; c < CHUNKS; ++c)
      gsum += ok ? (int)psrc8[(size_t)c * N_NODES + v] : 0;
    if (ok) norm[v] = 1.0f / (float)(gsum > 1 ? gsum : 1);
  }
}

// stateless streaming scatter: pos = row_start[dst] + delta8[chunk][dst] + rank8[e]
__global__ __launch_bounds__(256) void scatter_kernel(const int* __restrict__ src,
                                                      const int* __restrict__ dst,
                                                      const int* __restrict__ row_start,
                                                      const unsigned char* __restrict__ delta8,
                                                      const unsigned char* __restrict__ rank8,
                                                      int* __restrict__ eidx) {
  int tid = blockIdx.x * 256 + threadIdx.x;
  int e = tid * 4;
  if (e >= N_EDGES) return;
  int4 d4 = *(const int4*)(dst + e);
  int4 s4 = *(const int4*)(src + e);
  unsigned rr = *(const unsigned*)(rank8 + e);
  int dd[4] = {d4.x, d4.y, d4.z, d4.w};
  int ss[4] = {s4.x, s4.y, s4.z, s4.w};
#pragma unroll
  for (int k = 0; k < 4; ++k) {
    int c = (e + k) / EPC;  // EPC=6250 not /4: per-edge chunk id
    int d = dd[k];
    int pos = row_start[d] + (int)delta8[(size_t)c * N_NODES + d] + (int)((rr >> (8 * k)) & 0xFFu);
    eidx[pos] = ss[k];
  }
}

// h = (feat @ W) * norm[row], stored as bf16. No LDS.
// Block: 128 thr = 2 waves; wave handles 32 rows x 128 cols.
__global__ __launch_bounds__(128) void gemm_kernel(const float* __restrict__ feat,
                                                   const short* __restrict__ Wf,
                                                   const float* __restrict__ norm,
                                                   unsigned short* __restrict__ h) {
  int tid = threadIdx.x;
  int w = tid >> 6, l = tid & 63;
  int m = l & 15, q = l >> 4;
  long base = (long)blockIdx.x * 64 + w * 32;

  float4_t acc[2][8];
#pragma unroll
  for (int r = 0; r < 2; ++r)
#pragma unroll
    for (int t = 0; t < 8; ++t) acc[r][t] = (float4_t)(0.0f);

  long row0 = base + m;
  long row1 = base + 16 + m;
  long r0c = row0 < N_NODES - 1 ? row0 : N_NODES - 1;
  long r1c = row1 < N_NODES - 1 ? row1 : N_NODES - 1;
  const float* a0p = feat + (size_t)r0c * IN_F;
  const float* a1p = feat + (size_t)r1c * IN_F;
  const short8* bb = (const short8*)Wf;

#pragma unroll
  for (int s = 0; s < 8; ++s) {
    int k0 = s * 32 + q * 8;
    float4_t av0a = *(const float4_t*)(a0p + k0);
    float4_t av0b = *(const float4_t*)(a0p + k0 + 4);
    float4_t av1a = *(const float4_t*)(a1p + k0);
    float4_t av1b = *(const float4_t*)(a1p + k0 + 4);
    short8 fa0, fa1;
#pragma unroll
    for (int i = 0; i < 4; ++i) {
      fa0[i] = f2bf(av0a[i]);
      fa0[i + 4] = f2bf(av0b[i]);
      fa1[i] = f2bf(av1a[i]);
      fa1[i + 4] = f2bf(av1b[i]);
    }
#pragma unroll
    for (int t = 0; t < 8; ++t) {
      short8 fb = bb[((s * 8 + t) * 16 + m) * 4 + q];
      acc[0][t] = __builtin_amdgcn_mfma_f32_16x16x32_bf16(fa0, fb, acc[0][t], 0, 0, 0);
      acc[1][t] = __builtin_amdgcn_mfma_f32_16x16x32_bf16(fa1, fb, acc[1][t], 0, 0, 0);
    }
  }

  // C/D layout: col = lane&15 (=m), row = q*4 + i
#pragma unroll
  for (int r = 0; r < 2; ++r) {
#pragma unroll
    for (int i = 0; i < 4; ++i) {
      long row = base + r * 16 + q * 4 + i;
      if (row < N_NODES) {
        float nm = norm[row];
        size_t ho = (size_t)row * OUT_F;
#pragma unroll
        for (int t = 0; t < 8; ++t) {
          h[ho + t * 16 + m] = (unsigned short)f2bf(acc[r][t][i] * nm);
        }
      }
    }
  }
}

// One wave per dst node; wave processes 2 h-rows/step (32 lanes x 8 B each).
__global__ __launch_bounds__(256) void agg_kernel(const unsigned short* __restrict__ h,
                                                  const int* __restrict__ row_start,
                                                  const int* __restrict__ cnt,
                                                  const int* __restrict__ eidx,
                                                  const float* __restrict__ bias,
                                                  float* __restrict__ out) {
  int w = threadIdx.x >> 6, l = threadIdx.x & 63;
  int d = blockIdx.x * 4 + w;  // grid 12500 -> exactly 50000
  int rs = row_start[d], re = rs + cnt[d];
  const unsigned* __restrict__ hu = (const unsigned*)h;  // 64 uints per row
  int rowsel = l >> 5, cp = l & 31;  // lane covers cols 4*cp .. 4*cp+3
  float a0 = 0.f, a1 = 0.f, a2 = 0.f, a3 = 0.f;
  for (int bse = rs; bse < re; bse += 64) {
    int n = re - bse; if (n > 64) n = 64;
    int e = (l < n) ? eidx[bse + l] : 0;
    int half = (n + 1) >> 1;
    int j = 0;
    for (; j + 2 <= half; j += 2) {
      int i0 = 2 * j + rowsel;
      int i1 = i0 + 2;
      int s0 = __shfl(e, i0);
      int s1 = __shfl(e, i1);
      uint2 v0 = *(const uint2*)(hu + (size_t)s0 * 64 + 2 * cp);
      uint2 v1 = *(const uint2*)(hu + (size_t)s1 * 64 + 2 * cp);
      if (i0 >= n) { v0.x = 0; v0.y = 0; }
      if (i1 >= n) { v1.x = 0; v1.y = 0; }
      a0 += bflo(v0.x); a1 += bfhi(v0.x); a2 += bflo(v0.y); a3 += bfhi(v0.y);
      a0 += bflo(v1.x); a1 += bfhi(v1.x); a2 += bflo(v1.y); a3 += bfhi(v1.y);
    }
    for (; j < half; ++j) {
      int i0 = 2 * j + rowsel;
      int s0 = __shfl(e, i0);
      uint2 v0 = *(const uint2*)(hu + (size_t)s0 * 64 + 2 * cp);
      if (i0 >= n) { v0.x = 0; v0.y = 0; }
      a0 += bflo(v0.x); a1 += bfhi(v0.x); a2 += bflo(v0.y); a3 += bfhi(v0.y);
    }
  }
  a0 += __shfl_xor(a0, 32);
  a1 += __shfl_xor(a1, 32);
  a2 += __shfl_xor(a2, 32);
  a3 += __shfl_xor(a3, 32);
  if (rowsel == 0) {
    float4 bv = ((const float4*)bias)[cp];
    float4 o;
    o.x = a0 + bv.x; o.y = a1 + bv.y; o.z = a2 + bv.z; o.w = a3 + bv.w;
    ((float4*)(out + (size_t)d * OUT_F))[cp] = o;
  }
}

extern "C" void kernel_launch(void* const* d_in, const int* in_sizes, int n_in,
                              void* d_out, int out_size, void* d_ws, size_t ws_size,
                              hipStream_t stream) {
  const float* feat = (const float*)d_in[0];
  const float* weight = (const float*)d_in[1];
  const float* bias = (const float*)d_in[2];
  const int* src = (const int*)d_in[3];
  const int* dst = (const int*)d_in[4];
  float* out = (float*)d_out;

  char* ws = (char*)d_ws;
  size_t off = 0;
  auto alloc = [&](size_t bytes) -> void* {
    void* p = ws + off;
    off += (bytes + 511) & ~(size_t)511;
    return p;
  };
  int* cursor = (int*)alloc(4);
  int* cnt = (int*)alloc(N_NODES * 4);
  int* row_start = (int*)alloc(N_NODES * 4);
  float* norm = (float*)alloc(N_NODES * 4);
  int* eidx = (int*)alloc(N_EDGES * 4);
  short* Wf = (short*)alloc(IN_F * OUT_F * 2);
  unsigned short* h = (unsigned short*)alloc((size_t)N_NODES * OUT_F * 2);
  unsigned char* pdst8 = (unsigned char*)alloc((size_t)CHUNKS * N_NODES);
  unsigned char* psrc8 = (unsigned char*)alloc((size_t)CHUNKS * N_NODES);
  unsigned char* delta8 = (unsigned char*)alloc((size_t)CHUNKS * N_NODES);
  unsigned char* rank8 = (unsigned char*)alloc((size_t)N_EDGES);
  (void)off; (void)ws_size; (void)in_sizes; (void)n_in; (void)out_size;

  hipLaunchKernelGGL(hist_kernel, dim3(HIST_BLOCKS + 2), dim3(256), 0, stream,
                     src, dst, pdst8, psrc8, rank8, weight, Wf, cursor);
  hipLaunchKernelGGL(reduceoff_kernel, dim3(NGB, 2), dim3(256), 0, stream,
                     pdst8, psrc8, delta8, cnt, row_start, cursor, norm);
  hipLaunchKernelGGL(scatter_kernel, dim3((N_EDGES / 4 + 255) / 256), dim3(256), 0, stream,
                     src, dst, row_start, delta8, rank8, eidx);
  hipLaunchKernelGGL(gemm_kernel, dim3((N_NODES + 63) / 64), dim3(128), 0, stream, feat, Wf, norm, h);
  hipLaunchKernelGGL(agg_kernel, dim3(N_NODES / 4), dim3(256), 0, stream, h, row_start, cnt, eidx, bias, out);
}

// Round 8
// 186.495 us; speedup vs baseline: 1.1623x; 1.1623x over previous
//
#include <hip/hip_runtime.h>

#define N_NODES 50000
#define N_EDGES 800000
#define IN_F 256
#define OUT_F 128

#define CHUNKS 128
#define EPC (N_EDGES / CHUNKS)   // 6250 edges per chunk
#define BINW (N_NODES / 4)       // 12500 u32 words, 4 x u8 bins each (50 KB LDS)
#define NWORDS (N_NODES / 4)     // 12500 packed node-words
#define RGB 196                  // reduceoff blocks: 64 words (256 nodes) each
#define HIST_BLOCKS (2 * CHUNKS) // 256
#define CPW (CHUNKS / 4)         // 32 chunks per wave

typedef __attribute__((ext_vector_type(8))) short short8;
typedef __attribute__((ext_vector_type(4))) float float4_t;

// float -> bf16 round-to-nearest-even
__device__ __forceinline__ short f2bf(float f) {
  unsigned u = __builtin_bit_cast(unsigned, f);
  u = u + 0x7FFFu + ((u >> 16) & 1u);
  return (short)(u >> 16);
}

__device__ __forceinline__ float bflo(unsigned u) {
  return __builtin_bit_cast(float, u << 16);
}
__device__ __forceinline__ float bfhi(unsigned u) {
  return __builtin_bit_cast(float, u & 0xFFFF0000u);
}

// ---- histogram + per-edge rank (LDS-privatized u8 bins) + fused wprep ----
// blocks 0..255: b>>7 = side (0:dst, 1:src), b&127 = chunk. blocks 256..257: wprep.
__global__ __launch_bounds__(256) void hist_kernel(const int* __restrict__ src,
                                                   const int* __restrict__ dst,
                                                   unsigned char* __restrict__ pdst8,
                                                   unsigned char* __restrict__ psrc8,
                                                   unsigned char* __restrict__ rank8,
                                                   const float* __restrict__ W,
                                                   short* __restrict__ Wf,
                                                   int* __restrict__ cursor) {
  __shared__ unsigned bins[BINW];
  int b = blockIdx.x;
  int t = threadIdx.x;
  if (b >= HIST_BLOCKS) {  // wprep: 2 blocks cover 32768 elements; also zero cursor
    int bb = b - HIST_BLOCKS;
    if (bb == 0 && t == 0) *cursor = 0;
#pragma unroll
    for (int i = 0; i < 64; ++i) {
      int idx = bb * 16384 + i * 256 + t;
      int k = idx >> 7, n = idx & 127;
      int s = k >> 5, q = (k >> 3) & 3, j = k & 7;
      int tt = n >> 4, m = n & 15;
      Wf[(((s * 8 + tt) * 16 + m) * 32) + q * 8 + j] = f2bf(W[idx]);
    }
    return;
  }
  int h = b >> 7;
  int c = b & 127;
  for (int j = t; j < BINW; j += 256) bins[j] = 0;
  __syncthreads();
  const int* key = h ? src : dst;
  int e0 = c * EPC;

  auto process = [&](int v, int eI) {
    unsigned sh = (v & 3) * 8;
    unsigned old = atomicAdd(&bins[v >> 2], 1u << sh);
    if (!h) rank8[eI] = (unsigned char)((old >> sh) & 0xFFu);
  };

  // 6 full tiles of 1024 + tail of 106 (EPC = 6250)
#pragma unroll 2
  for (int tile = 0; tile < 6; ++tile) {
    int i = tile * 1024 + t;
    int k0 = key[e0 + i];
    int k1 = key[e0 + i + 256];
    int k2 = key[e0 + i + 512];
    int k3 = key[e0 + i + 768];
    process(k0, e0 + i);
    process(k1, e0 + i + 256);
    process(k2, e0 + i + 512);
    process(k3, e0 + i + 768);
  }
  {
    int i = 6144 + t;
    if (i < EPC) process(key[e0 + i], e0 + i);
  }
  __syncthreads();
  unsigned* p32 = (unsigned*)((h ? psrc8 : pdst8) + (size_t)c * N_NODES);
  for (int j = t; j < BINW; j += 256) p32[j] = bins[j];
}

// grid (RGB, 2). Wave-split chunk prefix with packed-byte (4-node) arithmetic.
// Counts are tiny (per-chunk <= ~7, in-degree <= ~50) so 4 u8 lanes ride in a
// u32 with no inter-byte carry. Wave w covers chunks [w*32, w*32+32); lane l
// covers packed word wd = g*64+l (nodes 4wd..4wd+3). Chain: 32 loads, reg-held.
// side 0: delta8, cnt, row_start (arrival-ordered base via 1 atomic/block).
// side 1: norm = 1/max(out_deg,1).
__global__ __launch_bounds__(256) void reduceoff_kernel(const unsigned char* __restrict__ pdst8,
                                                        const unsigned char* __restrict__ psrc8,
                                                        unsigned char* __restrict__ delta8,
                                                        int* __restrict__ cnt,
                                                        int* __restrict__ row_start,
                                                        int* __restrict__ cursor,
                                                        float* __restrict__ norm) {
  __shared__ unsigned tot[4][64];
  int g = blockIdx.x, side = blockIdx.y;
  int t = threadIdx.x;
  int w = t >> 6, l = t & 63;
  int wd = g * 64 + l;
  bool ok = wd < NWORDS;
  int wdc = ok ? wd : NWORDS - 1;  // clamp for safe addressing
  const unsigned* P = (const unsigned*)(side == 0 ? pdst8 : psrc8);

  unsigned vals[CPW];
  unsigned s = 0;
#pragma unroll
  for (int i = 0; i < CPW; ++i) {
    vals[i] = P[(size_t)(w * CPW + i) * NWORDS + wdc];
    s += vals[i];
  }
  tot[w][l] = s;
  __syncthreads();

  if (side == 0) {
    unsigned base = 0;
#pragma unroll
    for (int w2 = 0; w2 < 4; ++w2)
      if (w2 < w) base += tot[w2][l];
    unsigned run = base;
    unsigned* D = (unsigned*)delta8;
    if (ok) {
#pragma unroll
      for (int i = 0; i < CPW; ++i) {
        D[(size_t)(w * CPW + i) * NWORDS + wd] = run;
        run += vals[i];
      }
    }
    if (w == 0) {
      unsigned ftot = tot[0][l] + tot[1][l] + tot[2][l] + tot[3][l];
      if (!ok) ftot = 0;
      int c0 = ftot & 255, c1 = (ftot >> 8) & 255, c2 = (ftot >> 16) & 255, c3 = ftot >> 24;
      int T = c0 + c1 + c2 + c3;
      // wave-inclusive scan of T
      int x = T;
#pragma unroll
      for (int off = 1; off < 64; off <<= 1) {
        int y = __shfl_up(x, off);
        if (l >= off) x += y;
      }
      int waveTotal = __shfl(x, 63);
      int sb = 0;
      if (l == 63) sb = atomicAdd(cursor, waveTotal);
      sb = __shfl(sb, 63);
      int E = sb + x - T;  // exclusive prefix for this lane's 4 nodes
      if (ok) {
        int4 cv = {c0, c1, c2, c3};
        int4 rv = {E, E + c0, E + c0 + c1, E + c0 + c1 + c2};
        ((int4*)cnt)[wd] = cv;
        ((int4*)row_start)[wd] = rv;
      }
    }
  } else {
    if (w == 0 && ok) {
      unsigned ftot = tot[0][l] + tot[1][l] + tot[2][l] + tot[3][l];
      float4 nv;
      int d0 = ftot & 255, d1 = (ftot >> 8) & 255, d2 = (ftot >> 16) & 255, d3 = (int)(ftot >> 24);
      nv.x = 1.0f / (float)(d0 > 1 ? d0 : 1);
      nv.y = 1.0f / (float)(d1 > 1 ? d1 : 1);
      nv.z = 1.0f / (float)(d2 > 1 ? d2 : 1);
      nv.w = 1.0f / (float)(d3 > 1 ? d3 : 1);
      ((float4*)norm)[wd] = nv;
    }
  }
}

// stateless streaming scatter: pos = row_start[dst] + delta8[chunk][dst] + rank8[e]
__global__ __launch_bounds__(256) void scatter_kernel(const int* __restrict__ src,
                                                      const int* __restrict__ dst,
                                                      const int* __restrict__ row_start,
                                                      const unsigned char* __restrict__ delta8,
                                                      const unsigned char* __restrict__ rank8,
                                                      int* __restrict__ eidx) {
  int tid = blockIdx.x * 256 + threadIdx.x;
  int e = tid * 4;
  if (e >= N_EDGES) return;
  int4 d4 = *(const int4*)(dst + e);
  int4 s4 = *(const int4*)(src + e);
  unsigned rr = *(const unsigned*)(rank8 + e);
  int dd[4] = {d4.x, d4.y, d4.z, d4.w};
  int ss[4] = {s4.x, s4.y, s4.z, s4.w};
#pragma unroll
  for (int k = 0; k < 4; ++k) {
    int c = (e + k) / EPC;
    int d = dd[k];
    int pos = row_start[d] + (int)delta8[(size_t)c * N_NODES + d] + (int)((rr >> (8 * k)) & 0xFFu);
    eidx[pos] = ss[k];
  }
}

// h = (feat @ W) * norm[row], stored as bf16. No LDS.
// Block: 128 thr = 2 waves; wave handles 32 rows x 128 cols.
__global__ __launch_bounds__(128) void gemm_kernel(const float* __restrict__ feat,
                                                   const short* __restrict__ Wf,
                                                   const float* __restrict__ norm,
                                                   unsigned short* __restrict__ h) {
  int tid = threadIdx.x;
  int w = tid >> 6, l = tid & 63;
  int m = l & 15, q = l >> 4;
  long base = (long)blockIdx.x * 64 + w * 32;

  float4_t acc[2][8];
#pragma unroll
  for (int r = 0; r < 2; ++r)
#pragma unroll
    for (int t = 0; t < 8; ++t) acc[r][t] = (float4_t)(0.0f);

  long row0 = base + m;
  long row1 = base + 16 + m;
  long r0c = row0 < N_NODES - 1 ? row0 : N_NODES - 1;
  long r1c = row1 < N_NODES - 1 ? row1 : N_NODES - 1;
  const float* a0p = feat + (size_t)r0c * IN_F;
  const float* a1p = feat + (size_t)r1c * IN_F;
  const short8* bb = (const short8*)Wf;

#pragma unroll
  for (int s = 0; s < 8; ++s) {
    int k0 = s * 32 + q * 8;
    float4_t av0a = *(const float4_t*)(a0p + k0);
    float4_t av0b = *(const float4_t*)(a0p + k0 + 4);
    float4_t av1a = *(const float4_t*)(a1p + k0);
    float4_t av1b = *(const float4_t*)(a1p + k0 + 4);
    short8 fa0, fa1;
#pragma unroll
    for (int i = 0; i < 4; ++i) {
      fa0[i] = f2bf(av0a[i]);
      fa0[i + 4] = f2bf(av0b[i]);
      fa1[i] = f2bf(av1a[i]);
      fa1[i + 4] = f2bf(av1b[i]);
    }
#pragma unroll
    for (int t = 0; t < 8; ++t) {
      short8 fb = bb[((s * 8 + t) * 16 + m) * 4 + q];
      acc[0][t] = __builtin_amdgcn_mfma_f32_16x16x32_bf16(fa0, fb, acc[0][t], 0, 0, 0);
      acc[1][t] = __builtin_amdgcn_mfma_f32_16x16x32_bf16(fa1, fb, acc[1][t], 0, 0, 0);
    }
  }

  // C/D layout: col = lane&15 (=m), row = q*4 + i
#pragma unroll
  for (int r = 0; r < 2; ++r) {
#pragma unroll
    for (int i = 0; i < 4; ++i) {
      long row = base + r * 16 + q * 4 + i;
      if (row < N_NODES) {
        float nm = norm[row];
        size_t ho = (size_t)row * OUT_F;
#pragma unroll
        for (int t = 0; t < 8; ++t) {
          h[ho + t * 16 + m] = (unsigned short)f2bf(acc[r][t][i] * nm);
        }
      }
    }
  }
}

// One wave per dst node; wave processes 2 h-rows/step (32 lanes x 8 B each).
__global__ __launch_bounds__(256) void agg_kernel(const unsigned short* __restrict__ h,
                                                  const int* __restrict__ row_start,
                                                  const int* __restrict__ cnt,
                                                  const int* __restrict__ eidx,
                                                  const float* __restrict__ bias,
                                                  float* __restrict__ out) {
  int w = threadIdx.x >> 6, l = threadIdx.x & 63;
  int d = blockIdx.x * 4 + w;  // grid 12500 -> exactly 50000
  int rs = row_start[d], re = rs + cnt[d];
  const unsigned* __restrict__ hu = (const unsigned*)h;  // 64 uints per row
  int rowsel = l >> 5, cp = l & 31;  // lane covers cols 4*cp .. 4*cp+3
  float a0 = 0.f, a1 = 0.f, a2 = 0.f, a3 = 0.f;
  for (int bse = rs; bse < re; bse += 64) {
    int n = re - bse; if (n > 64) n = 64;
    int e = (l < n) ? eidx[bse + l] : 0;
    int half = (n + 1) >> 1;
    int j = 0;
    for (; j + 2 <= half; j += 2) {
      int i0 = 2 * j + rowsel;
      int i1 = i0 + 2;
      int s0 = __shfl(e, i0);
      int s1 = __shfl(e, i1);
      uint2 v0 = *(const uint2*)(hu + (size_t)s0 * 64 + 2 * cp);
      uint2 v1 = *(const uint2*)(hu + (size_t)s1 * 64 + 2 * cp);
      if (i0 >= n) { v0.x = 0; v0.y = 0; }
      if (i1 >= n) { v1.x = 0; v1.y = 0; }
      a0 += bflo(v0.x); a1 += bfhi(v0.x); a2 += bflo(v0.y); a3 += bfhi(v0.y);
      a0 += bflo(v1.x); a1 += bfhi(v1.x); a2 += bflo(v1.y); a3 += bfhi(v1.y);
    }
    for (; j < half; ++j) {
      int i0 = 2 * j + rowsel;
      int s0 = __shfl(e, i0);
      uint2 v0 = *(const uint2*)(hu + (size_t)s0 * 64 + 2 * cp);
      if (i0 >= n) { v0.x = 0; v0.y = 0; }
      a0 += bflo(v0.x); a1 += bfhi(v0.x); a2 += bflo(v0.y); a3 += bfhi(v0.y);
    }
  }
  a0 += __shfl_xor(a0, 32);
  a1 += __shfl_xor(a1, 32);
  a2 += __shfl_xor(a2, 32);
  a3 += __shfl_xor(a3, 32);
  if (rowsel == 0) {
    float4 bv = ((const float4*)bias)[cp];
    float4 o;
    o.x = a0 + bv.x; o.y = a1 + bv.y; o.z = a2 + bv.z; o.w = a3 + bv.w;
    ((float4*)(out + (size_t)d * OUT_F))[cp] = o;
  }
}

extern "C" void kernel_launch(void* const* d_in, const int* in_sizes, int n_in,
                              void* d_out, int out_size, void* d_ws, size_t ws_size,
                              hipStream_t stream) {
  const float* feat = (const float*)d_in[0];
  const float* weight = (const float*)d_in[1];
  const float* bias = (const float*)d_in[2];
  const int* src = (const int*)d_in[3];
  const int* dst = (const int*)d_in[4];
  float* out = (float*)d_out;

  char* ws = (char*)d_ws;
  size_t off = 0;
  auto alloc = [&](size_t bytes) -> void* {
    void* p = ws + off;
    off += (bytes + 511) & ~(size_t)511;
    return p;
  };
  int* cursor = (int*)alloc(4);
  int* cnt = (int*)alloc(N_NODES * 4);
  int* row_start = (int*)alloc(N_NODES * 4);
  float* norm = (float*)alloc(N_NODES * 4);
  int* eidx = (int*)alloc(N_EDGES * 4);
  short* Wf = (short*)alloc(IN_F * OUT_F * 2);
  unsigned short* h = (unsigned short*)alloc((size_t)N_NODES * OUT_F * 2);
  unsigned char* pdst8 = (unsigned char*)alloc((size_t)CHUNKS * N_NODES);
  unsigned char* psrc8 = (unsigned char*)alloc((size_t)CHUNKS * N_NODES);
  unsigned char* delta8 = (unsigned char*)alloc((size_t)CHUNKS * N_NODES);
  unsigned char* rank8 = (unsigned char*)alloc((size_t)N_EDGES);
  (void)off; (void)ws_size; (void)in_sizes; (void)n_in; (void)out_size;

  hipLaunchKernelGGL(hist_kernel, dim3(HIST_BLOCKS + 2), dim3(256), 0, stream,
                     src, dst, pdst8, psrc8, rank8, weight, Wf, cursor);
  hipLaunchKernelGGL(reduceoff_kernel, dim3(RGB, 2), dim3(256), 0, stream,
                     pdst8, psrc8, delta8, cnt, row_start, cursor, norm);
  hipLaunchKernelGGL(scatter_kernel, dim3((N_EDGES / 4 + 255) / 256), dim3(256), 0, stream,
                     src, dst, row_start, delta8, rank8, eidx);
  hipLaunchKernelGGL(gemm_kernel, dim3((N_NODES + 63) / 64), dim3(128), 0, stream, feat, Wf, norm, h);
  hipLaunchKernelGGL(agg_kernel, dim3(N_NODES / 4), dim3(256), 0, stream, h, row_start, cnt, eidx, bias, out);
}

// Round 9
// 185.100 us; speedup vs baseline: 1.1711x; 1.0075x over previous
//
#include <hip/hip_runtime.h>

#define N_NODES 50000
#define N_EDGES 800000
#define IN_F 256
#define OUT_F 128

#define CHUNKS 128
#define EPC (N_EDGES / CHUNKS)   // 6250 edges per chunk
#define BINW (N_NODES / 4)       // 12500 u32 words, 4 x u8 bins each (50 KB LDS)
#define NWORDS (N_NODES / 4)     // 12500 packed node-words
#define RGB 196                  // reduceoff blocks: 64 words (256 nodes) each
#define HIST_BLOCKS (2 * CHUNKS) // 256
#define CPW (CHUNKS / 4)         // 32 chunks per wave

#define GEMM_BLOCKS 391          // 128 rows each -> 50048 >= 50000
#define SCAT_BLOCKS 782          // 1024 edges each -> 800768 >= 800000

typedef __attribute__((ext_vector_type(8))) short short8;
typedef __attribute__((ext_vector_type(4))) float float4_t;

// float -> bf16 round-to-nearest-even
__device__ __forceinline__ short f2bf(float f) {
  unsigned u = __builtin_bit_cast(unsigned, f);
  u = u + 0x7FFFu + ((u >> 16) & 1u);
  return (short)(u >> 16);
}

__device__ __forceinline__ float bflo(unsigned u) {
  return __builtin_bit_cast(float, u << 16);
}
__device__ __forceinline__ float bfhi(unsigned u) {
  return __builtin_bit_cast(float, u & 0xFFFF0000u);
}

// ---- histogram + per-edge rank (LDS-privatized u8 bins) + fused wprep ----
// blocks 0..255: b>>7 = side (0:dst, 1:src), b&127 = chunk. blocks 256..257: wprep.
__global__ __launch_bounds__(256) void hist_kernel(const int* __restrict__ src,
                                                   const int* __restrict__ dst,
                                                   unsigned char* __restrict__ pdst8,
                                                   unsigned char* __restrict__ psrc8,
                                                   unsigned char* __restrict__ rank8,
                                                   const float* __restrict__ W,
                                                   short* __restrict__ Wf,
                                                   int* __restrict__ cursor) {
  __shared__ unsigned bins[BINW];
  int b = blockIdx.x;
  int t = threadIdx.x;
  if (b >= HIST_BLOCKS) {  // wprep: 2 blocks cover 32768 elements; also zero cursor
    int bb = b - HIST_BLOCKS;
    if (bb == 0 && t == 0) *cursor = 0;
#pragma unroll
    for (int i = 0; i < 64; ++i) {
      int idx = bb * 16384 + i * 256 + t;
      int k = idx >> 7, n = idx & 127;
      int s = k >> 5, q = (k >> 3) & 3, j = k & 7;
      int tt = n >> 4, m = n & 15;
      Wf[(((s * 8 + tt) * 16 + m) * 32) + q * 8 + j] = f2bf(W[idx]);
    }
    return;
  }
  int h = b >> 7;
  int c = b & 127;
  uint4* b4 = (uint4*)bins;
  for (int j = t; j < BINW / 4; j += 256) b4[j] = (uint4){0u, 0u, 0u, 0u};
  __syncthreads();
  const int* key = h ? src : dst;
  int e0 = c * EPC;

  auto process = [&](int v, int eI) {
    unsigned sh = (v & 3) * 8;
    unsigned old = atomicAdd(&bins[v >> 2], 1u << sh);
    if (!h) rank8[eI] = (unsigned char)((old >> sh) & 0xFFu);
  };

  // 6 full tiles of 1024 + tail of 106 (EPC = 6250)
#pragma unroll 2
  for (int tile = 0; tile < 6; ++tile) {
    int i = tile * 1024 + t;
    int k0 = key[e0 + i];
    int k1 = key[e0 + i + 256];
    int k2 = key[e0 + i + 512];
    int k3 = key[e0 + i + 768];
    process(k0, e0 + i);
    process(k1, e0 + i + 256);
    process(k2, e0 + i + 512);
    process(k3, e0 + i + 768);
  }
  {
    int i = 6144 + t;
    if (i < EPC) process(key[e0 + i], e0 + i);
  }
  __syncthreads();
  uint4* p128 = (uint4*)((h ? psrc8 : pdst8) + (size_t)c * N_NODES);  // rows 16B-aligned (50000%16==0)
  const uint4* s128 = (const uint4*)bins;
  for (int j = t; j < BINW / 4; j += 256) p128[j] = s128[j];
}

// grid (RGB, 2). Wave-split chunk prefix with packed-byte (4-node) arithmetic.
__global__ __launch_bounds__(256) void reduceoff_kernel(const unsigned char* __restrict__ pdst8,
                                                        const unsigned char* __restrict__ psrc8,
                                                        unsigned char* __restrict__ delta8,
                                                        int* __restrict__ cnt,
                                                        int* __restrict__ row_start,
                                                        int* __restrict__ cursor,
                                                        float* __restrict__ norm) {
  __shared__ unsigned tot[4][64];
  int g = blockIdx.x, side = blockIdx.y;
  int t = threadIdx.x;
  int w = t >> 6, l = t & 63;
  int wd = g * 64 + l;
  bool ok = wd < NWORDS;
  int wdc = ok ? wd : NWORDS - 1;  // clamp for safe addressing
  const unsigned* P = (const unsigned*)(side == 0 ? pdst8 : psrc8);

  unsigned vals[CPW];
  unsigned s = 0;
#pragma unroll
  for (int i = 0; i < CPW; ++i) {
    vals[i] = P[(size_t)(w * CPW + i) * NWORDS + wdc];
    s += vals[i];
  }
  tot[w][l] = s;
  __syncthreads();

  if (side == 0) {
    unsigned base = 0;
#pragma unroll
    for (int w2 = 0; w2 < 4; ++w2)
      if (w2 < w) base += tot[w2][l];
    unsigned run = base;
    unsigned* D = (unsigned*)delta8;
    if (ok) {
#pragma unroll
      for (int i = 0; i < CPW; ++i) {
        D[(size_t)(w * CPW + i) * NWORDS + wd] = run;
        run += vals[i];
      }
    }
    if (w == 0) {
      unsigned ftot = tot[0][l] + tot[1][l] + tot[2][l] + tot[3][l];
      if (!ok) ftot = 0;
      int c0 = ftot & 255, c1 = (ftot >> 8) & 255, c2 = (ftot >> 16) & 255, c3 = ftot >> 24;
      int T = c0 + c1 + c2 + c3;
      int x = T;
#pragma unroll
      for (int off = 1; off < 64; off <<= 1) {
        int y = __shfl_up(x, off);
        if (l >= off) x += y;
      }
      int waveTotal = __shfl(x, 63);
      int sb = 0;
      if (l == 63) sb = atomicAdd(cursor, waveTotal);
      sb = __shfl(sb, 63);
      int E = sb + x - T;
      if (ok) {
        int4 cv = {c0, c1, c2, c3};
        int4 rv = {E, E + c0, E + c0 + c1, E + c0 + c1 + c2};
        ((int4*)cnt)[wd] = cv;
        ((int4*)row_start)[wd] = rv;
      }
    }
  } else {
    if (w == 0 && ok) {
      unsigned ftot = tot[0][l] + tot[1][l] + tot[2][l] + tot[3][l];
      float4 nv;
      int d0 = ftot & 255, d1 = (ftot >> 8) & 255, d2 = (ftot >> 16) & 255, d3 = (int)(ftot >> 24);
      nv.x = 1.0f / (float)(d0 > 1 ? d0 : 1);
      nv.y = 1.0f / (float)(d1 > 1 ? d1 : 1);
      nv.z = 1.0f / (float)(d2 > 1 ? d2 : 1);
      nv.w = 1.0f / (float)(d3 > 1 ? d3 : 1);
      ((float4*)norm)[wd] = nv;
    }
  }
}

// ---- fused scatter + gemm (independent given reduceoff): one launch ----
// blocks [0, GEMM_BLOCKS): h = (feat @ W) * norm, 4 waves x 32 rows = 128 rows/block.
// blocks [GEMM_BLOCKS, GEMM_BLOCKS+SCAT_BLOCKS): stateless scatter, 4 edges/thread.
__global__ __launch_bounds__(256) void sg_kernel(const float* __restrict__ feat,
                                                 const short* __restrict__ Wf,
                                                 const float* __restrict__ norm,
                                                 unsigned short* __restrict__ h,
                                                 const int* __restrict__ src,
                                                 const int* __restrict__ dst,
                                                 const int* __restrict__ row_start,
                                                 const unsigned char* __restrict__ delta8,
                                                 const unsigned char* __restrict__ rank8,
                                                 int* __restrict__ eidx) {
  int b = blockIdx.x;
  int tid = threadIdx.x;
  if (b < GEMM_BLOCKS) {
    int w = tid >> 6, l = tid & 63;
    int m = l & 15, q = l >> 4;
    long base = (long)b * 128 + w * 32;

    float4_t acc[2][8];
#pragma unroll
    for (int r = 0; r < 2; ++r)
#pragma unroll
      for (int t = 0; t < 8; ++t) acc[r][t] = (float4_t)(0.0f);

    long row0 = base + m;
    long row1 = base + 16 + m;
    long r0c = row0 < N_NODES - 1 ? row0 : N_NODES - 1;
    long r1c = row1 < N_NODES - 1 ? row1 : N_NODES - 1;
    const float* a0p = feat + (size_t)r0c * IN_F;
    const float* a1p = feat + (size_t)r1c * IN_F;
    const short8* bb = (const short8*)Wf;

#pragma unroll
    for (int s = 0; s < 8; ++s) {
      int k0 = s * 32 + q * 8;
      float4_t av0a = *(const float4_t*)(a0p + k0);
      float4_t av0b = *(const float4_t*)(a0p + k0 + 4);
      float4_t av1a = *(const float4_t*)(a1p + k0);
      float4_t av1b = *(const float4_t*)(a1p + k0 + 4);
      short8 fa0, fa1;
#pragma unroll
      for (int i = 0; i < 4; ++i) {
        fa0[i] = f2bf(av0a[i]);
        fa0[i + 4] = f2bf(av0b[i]);
        fa1[i] = f2bf(av1a[i]);
        fa1[i + 4] = f2bf(av1b[i]);
      }
#pragma unroll
      for (int t = 0; t < 8; ++t) {
        short8 fb = bb[((s * 8 + t) * 16 + m) * 4 + q];
        acc[0][t] = __builtin_amdgcn_mfma_f32_16x16x32_bf16(fa0, fb, acc[0][t], 0, 0, 0);
        acc[1][t] = __builtin_amdgcn_mfma_f32_16x16x32_bf16(fa1, fb, acc[1][t], 0, 0, 0);
      }
    }

    // C/D layout: col = lane&15 (=m), row = q*4 + i
#pragma unroll
    for (int r = 0; r < 2; ++r) {
#pragma unroll
      for (int i = 0; i < 4; ++i) {
        long row = base + r * 16 + q * 4 + i;
        if (row < N_NODES) {
          float nm = norm[row];
          size_t ho = (size_t)row * OUT_F;
#pragma unroll
          for (int t = 0; t < 8; ++t) {
            h[ho + t * 16 + m] = (unsigned short)f2bf(acc[r][t][i] * nm);
          }
        }
      }
    }
  } else {
    int gt = (b - GEMM_BLOCKS) * 256 + tid;
    int e = gt * 4;
    if (e >= N_EDGES) return;
    int4 d4 = *(const int4*)(dst + e);
    int4 s4 = *(const int4*)(src + e);
    unsigned rr = *(const unsigned*)(rank8 + e);
    int dd[4] = {d4.x, d4.y, d4.z, d4.w};
    int ss[4] = {s4.x, s4.y, s4.z, s4.w};
#pragma unroll
    for (int k = 0; k < 4; ++k) {
      int c = (e + k) / EPC;
      int d = dd[k];
      int pos = row_start[d] + (int)delta8[(size_t)c * N_NODES + d] + (int)((rr >> (8 * k)) & 0xFFu);
      eidx[pos] = ss[k];
    }
  }
}

// One wave per dst node; lane-halves cover 2 rows, 8-row unrolled gather for MLP depth.
__global__ __launch_bounds__(256) void agg_kernel(const unsigned short* __restrict__ h,
                                                  const int* __restrict__ row_start,
                                                  const int* __restrict__ cnt,
                                                  const int* __restrict__ eidx,
                                                  const float* __restrict__ bias,
                                                  float* __restrict__ out) {
  int w = threadIdx.x >> 6, l = threadIdx.x & 63;
  int d = blockIdx.x * 4 + w;  // grid 12500 -> exactly 50000
  int rs = row_start[d], re = rs + cnt[d];
  const unsigned* __restrict__ hu = (const unsigned*)h;  // 64 uints per row
  int rowsel = l >> 5, cp = l & 31;  // lane covers cols 4*cp .. 4*cp+3
  float a0 = 0.f, a1 = 0.f, a2 = 0.f, a3 = 0.f;
  for (int bse = rs; bse < re; bse += 64) {
    int n = re - bse; if (n > 64) n = 64;
    int e = (l < n) ? eidx[bse + l] : 0;
    int half = (n + 1) >> 1;
    int j = 0;
    for (; j + 4 <= half; j += 4) {  // 8 rows per iteration, 4 gathers in flight
      int i0 = 2 * j + rowsel;
      int s0 = __shfl(e, i0);
      int s1 = __shfl(e, i0 + 2);
      int s2 = __shfl(e, i0 + 4);
      int s3 = __shfl(e, i0 + 6);
      uint2 v0 = *(const uint2*)(hu + (size_t)s0 * 64 + 2 * cp);
      uint2 v1 = *(const uint2*)(hu + (size_t)s1 * 64 + 2 * cp);
      uint2 v2 = *(const uint2*)(hu + (size_t)s2 * 64 + 2 * cp);
      uint2 v3 = *(const uint2*)(hu + (size_t)s3 * 64 + 2 * cp);
      if (i0 >= n) { v0.x = 0; v0.y = 0; }
      if (i0 + 2 >= n) { v1.x = 0; v1.y = 0; }
      if (i0 + 4 >= n) { v2.x = 0; v2.y = 0; }
      if (i0 + 6 >= n) { v3.x = 0; v3.y = 0; }
      a0 += bflo(v0.x); a1 += bfhi(v0.x); a2 += bflo(v0.y); a3 += bfhi(v0.y);
      a0 += bflo(v1.x); a1 += bfhi(v1.x); a2 += bflo(v1.y); a3 += bfhi(v1.y);
      a0 += bflo(v2.x); a1 += bfhi(v2.x); a2 += bflo(v2.y); a3 += bfhi(v2.y);
      a0 += bflo(v3.x); a1 += bfhi(v3.x); a2 += bflo(v3.y); a3 += bfhi(v3.y);
    }
    for (; j + 2 <= half; j += 2) {
      int i0 = 2 * j + rowsel;
      int i1 = i0 + 2;
      int s0 = __shfl(e, i0);
      int s1 = __shfl(e, i1);
      uint2 v0 = *(const uint2*)(hu + (size_t)s0 * 64 + 2 * cp);
      uint2 v1 = *(const uint2*)(hu + (size_t)s1 * 64 + 2 * cp);
      if (i0 >= n) { v0.x = 0; v0.y = 0; }
      if (i1 >= n) { v1.x = 0; v1.y = 0; }
      a0 += bflo(v0.x); a1 += bfhi(v0.x); a2 += bflo(v0.y); a3 += bfhi(v0.y);
      a0 += bflo(v1.x); a1 += bfhi(v1.x); a2 += bflo(v1.y); a3 += bfhi(v1.y);
    }
    for (; j < half; ++j) {
      int i0 = 2 * j + rowsel;
      int s0 = __shfl(e, i0);
      uint2 v0 = *(const uint2*)(hu + (size_t)s0 * 64 + 2 * cp);
      if (i0 >= n) { v0.x = 0; v0.y = 0; }
      a0 += bflo(v0.x); a1 += bfhi(v0.x); a2 += bflo(v0.y); a3 += bfhi(v0.y);
    }
  }
  a0 += __shfl_xor(a0, 32);
  a1 += __shfl_xor(a1, 32);
  a2 += __shfl_xor(a2, 32);
  a3 += __shfl_xor(a3, 32);
  if (rowsel == 0) {
    float4 bv = ((const float4*)bias)[cp];
    float4 o;
    o.x = a0 + bv.x; o.y = a1 + bv.y; o.z = a2 + bv.z; o.w = a3 + bv.w;
    ((float4*)(out + (size_t)d * OUT_F))[cp] = o;
  }
}

extern "C" void kernel_launch(void* const* d_in, const int* in_sizes, int n_in,
                              void* d_out, int out_size, void* d_ws, size_t ws_size,
                              hipStream_t stream) {
  const float* feat = (const float*)d_in[0];
  const float* weight = (const float*)d_in[1];
  const float* bias = (const float*)d_in[2];
  const int* src = (const int*)d_in[3];
  const int* dst = (const int*)d_in[4];
  float* out = (float*)d_out;

  char* ws = (char*)d_ws;
  size_t off = 0;
  auto alloc = [&](size_t bytes) -> void* {
    void* p = ws + off;
    off += (bytes + 511) & ~(size_t)511;
    return p;
  };
  int* cursor = (int*)alloc(4);
  int* cnt = (int*)alloc(N_NODES * 4);
  int* row_start = (int*)alloc(N_NODES * 4);
  float* norm = (float*)alloc(N_NODES * 4);
  int* eidx = (int*)alloc(N_EDGES * 4);
  short* Wf = (short*)alloc(IN_F * OUT_F * 2);
  unsigned short* h = (unsigned short*)alloc((size_t)N_NODES * OUT_F * 2);
  unsigned char* pdst8 = (unsigned char*)alloc((size_t)CHUNKS * N_NODES);
  unsigned char* psrc8 = (unsigned char*)alloc((size_t)CHUNKS * N_NODES);
  unsigned char* delta8 = (unsigned char*)alloc((size_t)CHUNKS * N_NODES);
  unsigned char* rank8 = (unsigned char*)alloc((size_t)N_EDGES);
  (void)off; (void)ws_size; (void)in_sizes; (void)n_in; (void)out_size;

  hipLaunchKernelGGL(hist_kernel, dim3(HIST_BLOCKS + 2), dim3(256), 0, stream,
                     src, dst, pdst8, psrc8, rank8, weight, Wf, cursor);
  hipLaunchKernelGGL(reduceoff_kernel, dim3(RGB, 2), dim3(256), 0, stream,
                     pdst8, psrc8, delta8, cnt, row_start, cursor, norm);
  hipLaunchKernelGGL(sg_kernel, dim3(GEMM_BLOCKS + SCAT_BLOCKS), dim3(256), 0, stream,
                     feat, Wf, norm, h, src, dst, row_start, delta8, rank8, eidx);
  hipLaunchKernelGGL(agg_kernel, dim3(N_NODES / 4), dim3(256), 0, stream, h, row_start, cnt, eidx, bias, out);
}